// Round 7
// baseline (68.576 us; speedup 1.0000x reference)
//
#include <hip/hip_runtime.h>

#define PNUM    1024
#define NB      128
#define NBLOCKS (NB * 16)

typedef _Float16 h2 __attribute__((ext_vector_type(2)));
typedef _Float16 h4 __attribute__((ext_vector_type(4)));

// gt LDS pad: +1 word every 4 (R3-proven layout, b32 reads)
#define PAD(k) ((k) + ((k) >> 2))
// pred LDS pad: +2 words per 64-element row -> W = 66*jslot + e_local.
// Affine per jslot (row-contiguous), banks 66j%32 = 2j (spread), 8B-aligned.

// smooth-L1 identity: sl1(d) = m*(|d| - 0.5m), m = min(|d|,1)   (5 packed ops)
#define SL1(acc, p, g) do {                               \
    h2 d_ = (p) - (g);                                    \
    h2 a_ = __builtin_elementwise_abs(d_);                \
    h2 m_ = __builtin_elementwise_min(a_, one2);          \
    h2 t_ = __builtin_elementwise_fma(m_, nh2, a_);       \
    (acc) = __builtin_elementwise_fma(m_, t_, (acc)); } while (0)

static __device__ __forceinline__ h2 to_h2(float2 f) {
  h2 r; r.x = (_Float16)f.x; r.y = (_Float16)f.y; return r;
}

// One block = (batch b, 64 consecutive shifts). 256 threads =
// 16 shift-slots (4 shifts each, rolling 7-wide gt window) x 16 j-slots (64 j each).
// NOTE: this is the R3 structure (proven 29us / VGPR 40). The 8-shift variant
// (R4-R6) compiles to a 20-VGPR latency-serialized body -- do not revisit.
__global__ __launch_bounds__(256) void poly_kernel(
    const float* __restrict__ pred, const float* __restrict__ gt,
    float* __restrict__ block_min, unsigned* __restrict__ counter,
    float* __restrict__ out) {
  __shared__ h2    pred_s[1054];     // 66*15+63 = 1053 max
  __shared__ h2    gt_s[1360];       // PAD(1087)=1358
  __shared__ float partial[16][64];  // 4 KB
  __shared__ int   lastflag;

  const int b     = blockIdx.x >> 4;
  const int chunk = blockIdx.x & 15;
  const int t     = threadIdx.x;

  const float2* pred2 = (const float2*)(pred + (size_t)b * (PNUM * 2));
  const float2* gt2   = (const float2*)(gt   + (size_t)b * (PNUM * 2));

  // Stage fp32 -> packed fp16 into LDS.
  #pragma unroll
  for (int k = t; k < PNUM; k += 256)
    pred_s[66 * (k >> 6) + (k & 63)] = to_h2(pred2[k]);
  const int gb = chunk * 64;
  for (int k = t; k < 1088; k += 256)           // elements [gb, gb+1087] wrapped
    gt_s[PAD(k)] = to_h2(gt2[(gb + k) & (PNUM - 1)]);
  __syncthreads();

  const int sslot = t & 15;            // shifts i = chunk*64 + 4*sslot + s, s=0..3
  const int jslot = t >> 4;            // j = jslot*64 + jj, jj=0..63
  const h2* Pp = pred_s + 66 * jslot;              // affine pred row
  const h2* Gp = gt_s + PAD(4 * sslot + 64 * jslot); // kbase%4==0 -> offsets fold

  const h2 one2 = {(_Float16)1.0f,  (_Float16)1.0f};
  const h2 nh2  = {(_Float16)-0.5f, (_Float16)-0.5f};
  h2 a0 = {(_Float16)0.0f, (_Float16)0.0f};
  h2 a1 = a0, a2 = a0, a3 = a0;

  // window: w holds gt elements kbase+e0 .. +2 (PAD(0..2)=0,1,2)
  h2 w0 = Gp[0], w1 = Gp[1], w2 = Gp[2];

  for (int g = 0; g < 16; ++g) {       // 16 groups x 4 jj = 64 j per thread
    h4 pa = *(const h4*)(Pp);          // pred elements e0, e0+1  (ds_read_b64)
    h4 pb = *(const h4*)(Pp + 2);      // pred elements e0+2, e0+3
    h2 p0 = pa.xy, p1 = pa.zw, p2 = pb.xy, p3 = pb.zw;
    h2 w3 = Gp[3];                     // gt element e0+3 (PAD(3)=3)
    SL1(a0, p0, w0); SL1(a1, p0, w1); SL1(a2, p0, w2); SL1(a3, p0, w3);
    h2 n0 = Gp[5];                     // element e0+4 (PAD(4)=5)
    SL1(a0, p1, w1); SL1(a1, p1, w2); SL1(a2, p1, w3); SL1(a3, p1, n0);
    h2 n1 = Gp[6];                     // element e0+5
    SL1(a0, p2, w2); SL1(a1, p2, w3); SL1(a2, p2, n0); SL1(a3, p2, n1);
    h2 n2 = Gp[7];                     // element e0+6
    SL1(a0, p3, w3); SL1(a1, p3, n0); SL1(a2, p3, n1); SL1(a3, p3, n2);
    w0 = n0; w1 = n1; w2 = n2;
    Gp += 5; Pp += 4;                  // 4 elements: gt +5 padded words, pred +4
  }

  // flush fp16 accumulators to fp32 partials: partial[jslot][local_shift]
  {
    const int ls = sslot * 4;
    partial[jslot][ls + 0] = (float)a0.x + (float)a0.y;
    partial[jslot][ls + 1] = (float)a1.x + (float)a1.y;
    partial[jslot][ls + 2] = (float)a2.x + (float)a2.y;
    partial[jslot][ls + 3] = (float)a3.x + (float)a3.y;
  }
  __syncthreads();

  // ---- per-block: sum 16 j-slot partials per shift, min over 64 shifts
  if (t < 64) {
    float s = 0.0f;
    #pragma unroll
    for (int q = 0; q < 16; ++q) s += partial[q][t];
    float dis = s * (1.0f / 1024.0f);
    #pragma unroll
    for (int off = 32; off; off >>= 1)
      dis = fminf(dis, __shfl_xor(dis, off));
    if (t == 0) {
      __hip_atomic_store(&block_min[blockIdx.x], dis,
                         __ATOMIC_RELEASE, __HIP_MEMORY_SCOPE_AGENT);
      unsigned old = __hip_atomic_fetch_add(counter, 1u,
                         __ATOMIC_ACQ_REL, __HIP_MEMORY_SCOPE_AGENT);
      lastflag = (old == NBLOCKS - 1);
    }
  }
  __syncthreads();

  // ---- last block: per-batch min over 16 chunks, mean over 128 batches
  if (lastflag) {
    float m = 0.0f;
    if (t < NB) {
      m = __hip_atomic_load(&block_min[t * 16],
                            __ATOMIC_ACQUIRE, __HIP_MEMORY_SCOPE_AGENT);
      #pragma unroll
      for (int c = 1; c < 16; ++c) {
        float v = __hip_atomic_load(&block_min[t * 16 + c],
                                    __ATOMIC_ACQUIRE, __HIP_MEMORY_SCOPE_AGENT);
        m = fminf(m, v);
      }
    }
    #pragma unroll
    for (int off = 32; off; off >>= 1) m += __shfl_xor(m, off);
    if (t < NB && (t & 63) == 0) partial[0][t >> 6] = m;
    __syncthreads();
    if (t == 0) out[0] = (partial[0][0] + partial[0][1]) * (1.0f / NB);
  }
}

extern "C" void kernel_launch(void* const* d_in, const int* in_sizes, int n_in,
                              void* d_out, int out_size, void* d_ws, size_t ws_size,
                              hipStream_t stream) {
  const float* pred = (const float*)d_in[0];
  const float* gt   = (const float*)d_in[1];
  float* out        = (float*)d_out;
  float* block_min  = (float*)d_ws;                          // 2048 floats
  unsigned* counter = (unsigned*)((char*)d_ws + NBLOCKS * 4);

  hipMemsetAsync(counter, 0, 4, stream);
  poly_kernel<<<NBLOCKS, 256, 0, stream>>>(pred, gt, block_min, counter, out);
}

// Round 8
// 68.401 us; speedup vs baseline: 1.0026x; 1.0026x over previous
//
#include <hip/hip_runtime.h>

#define PNUM    1024
#define NB      128
#define NBLOCKS (NB * 16)

typedef _Float16 h2 __attribute__((ext_vector_type(2)));

// padded LDS index: +1 word every 4 elements (exact R3 layout)
#define PAD(k) ((k) + ((k) >> 2))

// smooth-L1 identity: sl1(d) = m*(|d| - 0.5m), m = min(|d|,1)   (5 packed ops)
#define SL1(acc, p, g) do {                               \
    h2 d_ = (p) - (g);                                    \
    h2 a_ = __builtin_elementwise_abs(d_);                \
    h2 m_ = __builtin_elementwise_min(a_, one2);          \
    h2 t_ = __builtin_elementwise_fma(m_, nh2, a_);       \
    (acc) = __builtin_elementwise_fma(m_, t_, (acc)); } while (0)

static __device__ __forceinline__ h2 to_h2(float2 f) {
  h2 r; r.x = (_Float16)f.x; r.y = (_Float16)f.y; return r;
}

// EXACT R3 kernel body (29.3us proven) + fused atomic-tail reduce.
// Single delta vs R3: the tail. If this lands ~64us, agent-scope atomics in
// the function are the codegen trap (all slow builds R4-R7 contained them).
__global__ __launch_bounds__(256) void poly_kernel(
    const float* __restrict__ pred, const float* __restrict__ gt,
    float* __restrict__ block_min, unsigned* __restrict__ counter,
    float* __restrict__ out) {
  __shared__ h2    pred_s[1280];      // PAD(1023)=1278
  __shared__ h2    gt_s[1360];        // PAD(1087)=1358
  __shared__ float partial[16][64];
  __shared__ int   lastflag;

  const int b     = blockIdx.x >> 4;
  const int chunk = blockIdx.x & 15;
  const int t     = threadIdx.x;

  const float2* pred2 = (const float2*)(pred + (size_t)b * (PNUM * 2));
  const float2* gt2   = (const float2*)(gt   + (size_t)b * (PNUM * 2));

  // Stage fp32 -> packed fp16 into padded LDS (exact R3).
  #pragma unroll
  for (int k = t; k < PNUM; k += 256)
    pred_s[PAD(k)] = to_h2(pred2[k]);
  const int gb = chunk * 64;
  for (int k = t; k < 1088; k += 256)
    gt_s[PAD(k)] = to_h2(gt2[(gb + k) & (PNUM - 1)]);
  __syncthreads();

  const int sslot = t & 15;            // 4 consecutive shifts: i0 = chunk*64 + 4*sslot
  const int jslot = t >> 4;            // 64 consecutive j:   j0 = 64*jslot
  const int kbase = sslot * 4 + jslot * 64;
  int A = PAD(kbase);
  int P = PAD(jslot * 64);

  const h2 one2 = { (_Float16)1.0f,  (_Float16)1.0f };
  const h2 nh2  = { (_Float16)-0.5f, (_Float16)-0.5f };
  h2 acc0 = { (_Float16)0.0f, (_Float16)0.0f };
  h2 acc1 = acc0, acc2 = acc0, acc3 = acc0;

  // rolling window: w holds gt elements kbase+jj .. +3
  h2 w0 = gt_s[A], w1 = gt_s[A + 1], w2 = gt_s[A + 2];

  for (int g = 0; g < 16; ++g) {       // 16 groups x 4 jj = 64 j per thread
    h2 p0 = pred_s[P];
    h2 w3 = gt_s[A + 3];
    SL1(acc0, p0, w0); SL1(acc1, p0, w1); SL1(acc2, p0, w2); SL1(acc3, p0, w3);
    h2 p1 = pred_s[P + 1];
    h2 n0 = gt_s[A + 5];
    SL1(acc0, p1, w1); SL1(acc1, p1, w2); SL1(acc2, p1, w3); SL1(acc3, p1, n0);
    h2 p2 = pred_s[P + 2];
    h2 n1 = gt_s[A + 6];
    SL1(acc0, p2, w2); SL1(acc1, p2, w3); SL1(acc2, p2, n0); SL1(acc3, p2, n1);
    h2 p3 = pred_s[P + 3];
    h2 n2 = gt_s[A + 7];
    SL1(acc0, p3, w3); SL1(acc1, p3, n0); SL1(acc2, p3, n1); SL1(acc3, p3, n2);
    w0 = n0; w1 = n1; w2 = n2;
    A += 5; P += 5;
  }

  // flush fp16 accumulators to fp32 partials: partial[jslot][local_shift]
  {
    const int ls = sslot * 4;
    partial[jslot][ls + 0] = (float)acc0.x + (float)acc0.y;
    partial[jslot][ls + 1] = (float)acc1.x + (float)acc1.y;
    partial[jslot][ls + 2] = (float)acc2.x + (float)acc2.y;
    partial[jslot][ls + 3] = (float)acc3.x + (float)acc3.y;
  }
  __syncthreads();

  if (t < 64) {                        // wave 0: sum 16 j-slot partials per shift
    float s = 0.0f;
    #pragma unroll
    for (int q = 0; q < 16; ++q) s += partial[q][t];
    float dis = s * (1.0f / 1024.0f);
    #pragma unroll
    for (int off = 32; off; off >>= 1)
      dis = fminf(dis, __shfl_xor(dis, off));
    if (t == 0) {
      __hip_atomic_store(&block_min[blockIdx.x], dis,
                         __ATOMIC_RELEASE, __HIP_MEMORY_SCOPE_AGENT);
      unsigned old = __hip_atomic_fetch_add(counter, 1u,
                         __ATOMIC_ACQ_REL, __HIP_MEMORY_SCOPE_AGENT);
      lastflag = (old == NBLOCKS - 1);
    }
  }
  __syncthreads();

  // ---- last block: per-batch min over 16 chunks, mean over 128 batches
  if (lastflag) {
    float m = 0.0f;
    if (t < NB) {
      m = __hip_atomic_load(&block_min[t * 16],
                            __ATOMIC_ACQUIRE, __HIP_MEMORY_SCOPE_AGENT);
      #pragma unroll
      for (int c = 1; c < 16; ++c) {
        float v = __hip_atomic_load(&block_min[t * 16 + c],
                                    __ATOMIC_ACQUIRE, __HIP_MEMORY_SCOPE_AGENT);
        m = fminf(m, v);
      }
    }
    #pragma unroll
    for (int off = 32; off; off >>= 1) m += __shfl_xor(m, off);
    if (t < NB && (t & 63) == 0) partial[0][t >> 6] = m;
    __syncthreads();
    if (t == 0) out[0] = (partial[0][0] + partial[0][1]) * (1.0f / NB);
  }
}

extern "C" void kernel_launch(void* const* d_in, const int* in_sizes, int n_in,
                              void* d_out, int out_size, void* d_ws, size_t ws_size,
                              hipStream_t stream) {
  const float* pred = (const float*)d_in[0];
  const float* gt   = (const float*)d_in[1];
  float* out        = (float*)d_out;
  float* block_min  = (float*)d_ws;                          // 2048 floats
  unsigned* counter = (unsigned*)((char*)d_ws + NBLOCKS * 4);

  hipMemsetAsync(counter, 0, 4, stream);
  poly_kernel<<<NBLOCKS, 256, 0, stream>>>(pred, gt, block_min, counter, out);
}

// Round 9
// 28.274 us; speedup vs baseline: 2.4254x; 2.4193x over previous
//
#include <hip/hip_runtime.h>

#define PNUM    1024
#define NB      128
#define NBLOCKS (NB * 16)

typedef _Float16 h2 __attribute__((ext_vector_type(2)));

// padded LDS word index: +1 word every 8 -> gt banks (9s+4j+e)%32 = 2 lanes/bank (free)
#define PW(e) ((e) + ((e) >> 3))

// smooth-L1 identity: sl1(d) = m*(|d| - 0.5m), m = min(|d|,1)   (5 packed ops)
#define SL1(acc, p, g) do {                               \
    h2 d_ = (p) - (g);                                    \
    h2 a_ = __builtin_elementwise_abs(d_);                \
    h2 m_ = __builtin_elementwise_min(a_, one2);          \
    h2 t_ = __builtin_elementwise_fma(m_, nh2, a_);       \
    (acc) = __builtin_elementwise_fma(m_, t_, (acc)); } while (0)

// One group: pred elements e0..e0+3 vs window vars n0..n10 = gt elements
// kbase+e0 .. kbase+e0+10. Loads n7..n10 fresh.
#define GROUP(e0, n0,n1,n2,n3,n4,n5,n6,n7,n8,n9,n10) do {            \
    h2 p0 = Pp[PW(e0)], p1 = Pp[PW((e0)+1)];                         \
    h2 p2 = Pp[PW((e0)+2)], p3 = Pp[PW((e0)+3)];                     \
    n7  = Gp[PW((e0)+7)];  n8  = Gp[PW((e0)+8)];                     \
    n9  = Gp[PW((e0)+9)];  n10 = Gp[PW((e0)+10)];                    \
    SL1(a0,p0,n0); SL1(a1,p0,n1); SL1(a2,p0,n2); SL1(a3,p0,n3);      \
    SL1(a4,p0,n4); SL1(a5,p0,n5); SL1(a6,p0,n6); SL1(a7,p0,n7);      \
    SL1(a0,p1,n1); SL1(a1,p1,n2); SL1(a2,p1,n3); SL1(a3,p1,n4);      \
    SL1(a4,p1,n5); SL1(a5,p1,n6); SL1(a6,p1,n7); SL1(a7,p1,n8);      \
    SL1(a0,p2,n2); SL1(a1,p2,n3); SL1(a2,p2,n4); SL1(a3,p2,n5);      \
    SL1(a4,p2,n6); SL1(a5,p2,n7); SL1(a6,p2,n8); SL1(a7,p2,n9);      \
    SL1(a0,p3,n3); SL1(a1,p3,n4); SL1(a2,p3,n5); SL1(a3,p3,n6);      \
    SL1(a4,p3,n7); SL1(a5,p3,n8); SL1(a6,p3,n9); SL1(a7,p3,n10);     \
  } while (0)

// One block = (batch b, 64 consecutive shifts). 256 threads =
// 8 shift-slots (8 shifts each, rolling 11-wide gt window) x 32 j-slots (32 j each).
// NO atomics anywhere in this kernel: R8 bisection proved the fused
// agent-scope atomic tail collapses codegen to a 20-VGPR serialized body.
__global__ __launch_bounds__(256) void poly_cost_kernel(
    const float* __restrict__ pred, const float* __restrict__ gt,
    float* __restrict__ block_min) {
  __shared__ h2    pred_s[1151];     // PW(1023)=1150
  __shared__ h2    gt_s[1223];       // PW(1087)=1222
  __shared__ float partial[4][64];

  const int b     = blockIdx.x >> 4;
  const int chunk = blockIdx.x & 15;
  const int t     = threadIdx.x;

  const float4* pred4 = (const float4*)(pred + (size_t)b * (PNUM * 2));
  const float4* gt4   = (const float4*)(gt   + (size_t)b * (PNUM * 2));
  const int gb2 = chunk * 32;        // gt float4 base

  #pragma unroll
  for (int r = 0; r < 2; ++r) {
    int p = t + r * 256;
    float4 v = pred4[p];
    int w = PW(2 * p);               // 2p even -> pair never crosses pad boundary
    pred_s[w]     = h2{(_Float16)v.x, (_Float16)v.y};
    pred_s[w + 1] = h2{(_Float16)v.z, (_Float16)v.w};
  }
  #pragma unroll
  for (int r = 0; r < 2; ++r) {
    int u = t + r * 256;
    float4 v = gt4[(gb2 + u) & 511];
    int w = PW(2 * u);
    gt_s[w]     = h2{(_Float16)v.x, (_Float16)v.y};
    gt_s[w + 1] = h2{(_Float16)v.z, (_Float16)v.w};
  }
  if (t < 32) {
    int u = t + 512;
    float4 v = gt4[(gb2 + u) & 511];
    int w = PW(2 * u);
    gt_s[w]     = h2{(_Float16)v.x, (_Float16)v.y};
    gt_s[w + 1] = h2{(_Float16)v.z, (_Float16)v.w};
  }
  __syncthreads();

  const int sslot = t & 7;           // shifts i = chunk*64 + sslot*8 + s, s=0..7
  const int jslot = t >> 3;          // j = jslot*32 + jj, jj=0..31
  const h2* Pp = pred_s + 36 * jslot;             // PW(32*jslot)
  const h2* Gp = gt_s   + 9 * sslot + 36 * jslot; // PW(8*sslot+32*jslot)

  const h2 one2 = {(_Float16)1.0f,  (_Float16)1.0f};
  const h2 nh2  = {(_Float16)-0.5f, (_Float16)-0.5f};
  h2 a0 = {(_Float16)0.0f, (_Float16)0.0f};
  h2 a1 = a0, a2 = a0, a3 = a0, a4 = a0, a5 = a0, a6 = a0, a7 = a0;

  // window vars w0..w10; preload gt elements 0..6
  h2 w0 = Gp[PW(0)], w1 = Gp[PW(1)], w2 = Gp[PW(2)], w3 = Gp[PW(3)];
  h2 w4 = Gp[PW(4)], w5 = Gp[PW(5)], w6 = Gp[PW(6)];
  h2 w7, w8, w9, w10;

  // rotation by 4 mod 11: start indices 0,4,8,1,5,9,2,6
  GROUP( 0, w0,w1,w2,w3,w4,w5,w6,w7,w8,w9,w10);
  GROUP( 4, w4,w5,w6,w7,w8,w9,w10,w0,w1,w2,w3);
  GROUP( 8, w8,w9,w10,w0,w1,w2,w3,w4,w5,w6,w7);
  GROUP(12, w1,w2,w3,w4,w5,w6,w7,w8,w9,w10,w0);
  GROUP(16, w5,w6,w7,w8,w9,w10,w0,w1,w2,w3,w4);
  GROUP(20, w9,w10,w0,w1,w2,w3,w4,w5,w6,w7,w8);
  GROUP(24, w2,w3,w4,w5,w6,w7,w8,w9,w10,w0,w1);
  GROUP(28, w6,w7,w8,w9,w10,w0,w1,w2,w3,w4,w5);

  // ---- reduce over jslot (lane bits 3..5) via shuffles, named floats only
  float f0 = (float)a0.x + (float)a0.y, f1 = (float)a1.x + (float)a1.y;
  float f2 = (float)a2.x + (float)a2.y, f3 = (float)a3.x + (float)a3.y;
  float f4 = (float)a4.x + (float)a4.y, f5 = (float)a5.x + (float)a5.y;
  float f6 = (float)a6.x + (float)a6.y, f7 = (float)a7.x + (float)a7.y;
#define JRED(f) f += __shfl_xor(f, 8); f += __shfl_xor(f, 16); f += __shfl_xor(f, 32)
  JRED(f0); JRED(f1); JRED(f2); JRED(f3); JRED(f4); JRED(f5); JRED(f6); JRED(f7);
#undef JRED

  const int wid = t >> 6, lane = t & 63;
  if ((lane & 56) == 0) {            // lanes 0..7: sslot = lane
    float* pp = &partial[wid][lane * 8];
    pp[0] = f0; pp[1] = f1; pp[2] = f2; pp[3] = f3;
    pp[4] = f4; pp[5] = f5; pp[6] = f6; pp[7] = f7;
  }
  __syncthreads();

  // ---- per-block: sum 4 wave-partials per shift, min over 64 shifts
  if (t < 64) {
    float sum = partial[0][t] + partial[1][t] + partial[2][t] + partial[3][t];
    float dis = sum * (1.0f / 1024.0f);
    #pragma unroll
    for (int off = 32; off; off >>= 1)
      dis = fminf(dis, __shfl_xor(dis, off));
    if (t == 0) block_min[blockIdx.x] = dis;   // plain store, no atomics
  }
}

// Kernel 2: per-batch min over 16 block-mins, then mean over 128 batches.
__global__ __launch_bounds__(128) void poly_reduce_kernel(
    const float* __restrict__ block_min, float* __restrict__ out) {
  const int b = threadIdx.x;
  float m = block_min[b * 16];
  #pragma unroll
  for (int c = 1; c < 16; ++c) m = fminf(m, block_min[b * 16 + c]);
  #pragma unroll
  for (int off = 32; off; off >>= 1) m += __shfl_xor(m, off);
  __shared__ float wsum[2];
  if ((b & 63) == 0) wsum[b >> 6] = m;
  __syncthreads();
  if (b == 0) out[0] = (wsum[0] + wsum[1]) * (1.0f / NB);
}

extern "C" void kernel_launch(void* const* d_in, const int* in_sizes, int n_in,
                              void* d_out, int out_size, void* d_ws, size_t ws_size,
                              hipStream_t stream) {
  const float* pred = (const float*)d_in[0];
  const float* gt   = (const float*)d_in[1];
  float* out        = (float*)d_out;
  float* block_min  = (float*)d_ws;   // 2048 floats

  poly_cost_kernel<<<NBLOCKS, 256, 0, stream>>>(pred, gt, block_min);
  poly_reduce_kernel<<<1, 128, 0, stream>>>(block_min, out);
}